// Round 3
// baseline (384.323 us; speedup 1.0000x reference)
//
#include <hip/hip_runtime.h>
#include <cstdint>

// Exact radix-select (11+13+8 bits) on order-transformed x bits among t<0
// entries (t=-1 exactly in this problem => negative_loss = softplus(x),
// strictly increasing in x). Scans fused into the heavy kernels via a
// last-block ticket (device-scope atomics). Final pass uses fast
// __expf/__logf for VALUES and exact x-bit compare for the MASK, with a
// precise log1pf re-check only inside a 256-ulp guard band at the boundary.
//
// ws layout:
//   [0     ..  8192)  hist1 (2048 u32)
//   [8192  .. 40960)  hist2 (8192 u32)
//   [40960 .. 41984)  hist3 (256 u32)
//   [41984 .. 42048)  SelState
//   [42112 .. 42124)  tickets[3]
//   [49152 .. 49152+4N)  cached u-vals (0 sentinel for t>=0)

struct SelState {
    uint32_t prefix;   // selected high bits so far
    uint32_t k_rem;    // remaining rank within selected bin
    uint32_t u_kth;    // final: transformed bits of k-th largest x
    float    thr_nl;   // final: precise loss-space threshold
    uint32_t done;
};

#define GUARD 256u

__device__ __forceinline__ uint32_t xform(uint32_t b) {
    return ((int32_t)b < 0) ? ~b : (b | 0x80000000u);
}
__device__ __forceinline__ float unxform(uint32_t u) {
    uint32_t b = (u & 0x80000000u) ? (u ^ 0x80000000u) : ~u;
    return __uint_as_float(b);
}
// precise chain — must match the reference's fp32 semantics (used for the
// threshold value and the rare guard-band compare only)
__device__ __forceinline__ float neg_loss_precise(float x, float t) {
#pragma clang fp contract(off)
    return (fmaxf(-x, 0.0f) - x * t) + log1pf(expf(-fabsf(x)));
}

// last block of a grid selects the bin holding the k-th LARGEST element.
// hist read via atomic adds (device-coherent). part = 256-entry LDS scratch,
// sel = {bin, krem, total} LDS. No writer to sel[0..1] if k==0 or k>total.
template<int NBINS>
__device__ void select_kth(uint32_t* hist, uint32_t k, uint32_t* part, uint32_t* sel) {
    const int tid = threadIdx.x;
    constexpr int CH = NBINS / 256;
    uint32_t cnt[CH];
    uint32_t lsum = 0;
#pragma unroll
    for (int j = 0; j < CH; ++j) {
        cnt[j] = atomicAdd(&hist[tid * CH + j], 0u);
        lsum += cnt[j];
    }
    part[tid] = lsum;
    __syncthreads();
    for (int off = 1; off < 256; off <<= 1) {   // inclusive suffix sum
        uint32_t add = (tid + off < 256) ? part[tid + off] : 0u;
        __syncthreads();
        part[tid] += add;
        __syncthreads();
    }
    if (tid == 0) sel[2] = part[0];
    uint32_t A = (tid < 255) ? part[tid + 1] : 0u;  // strictly-above count
#pragma unroll
    for (int j = CH - 1; j >= 0; --j) {
        uint32_t c = cnt[j];
        if (A < k && k <= A + c) {  // exactly one (thread,bin) hits
            sel[0] = (uint32_t)(tid * CH + j);
            sel[1] = k - A;
        }
        A += c;
    }
    __syncthreads();
}

__global__ __launch_bounds__(256) void k1_hist(
        const float* __restrict__ x, const float* __restrict__ t,
        uint32_t* __restrict__ uvals, uint32_t* __restrict__ hist,
        uint32_t* __restrict__ ticket, SelState* __restrict__ st,
        const int* __restrict__ kptr, int n) {
    __shared__ uint32_t lh[4 * 2049];   // 4-way replicated 11-bit hist (+1 pad)
    __shared__ uint32_t s_last, sk;
    for (int i = threadIdx.x; i < 4 * 2049; i += 256) lh[i] = 0;
    __syncthreads();
    uint32_t* my = &lh[(threadIdx.x & 3) * 2049];

    const int n4 = n >> 2;
    const int stride = gridDim.x * 256;
    for (int i = blockIdx.x * 256 + threadIdx.x; i < n4; i += stride) {
        float4 xv = ((const float4*)x)[i];
        float4 tv = ((const float4*)t)[i];
        uint32_t u0 = (tv.x < 0.0f) ? xform(__float_as_uint(xv.x)) : 0u;
        uint32_t u1 = (tv.y < 0.0f) ? xform(__float_as_uint(xv.y)) : 0u;
        uint32_t u2 = (tv.z < 0.0f) ? xform(__float_as_uint(xv.z)) : 0u;
        uint32_t u3 = (tv.w < 0.0f) ? xform(__float_as_uint(xv.w)) : 0u;
        if (uvals) ((uint4*)uvals)[i] = make_uint4(u0, u1, u2, u3);
        if (u0) atomicAdd(&my[u0 >> 21], 1u);
        if (u1) atomicAdd(&my[u1 >> 21], 1u);
        if (u2) atomicAdd(&my[u2 >> 21], 1u);
        if (u3) atomicAdd(&my[u3 >> 21], 1u);
    }
    if (blockIdx.x == 0) {  // tail
        for (int i = (n4 << 2) + threadIdx.x; i < n; i += 256) {
            uint32_t u = (t[i] < 0.0f) ? xform(__float_as_uint(x[i])) : 0u;
            if (uvals) uvals[i] = u;
            if (u) atomicAdd(&my[u >> 21], 1u);
        }
    }
    __syncthreads();
    for (int i = threadIdx.x; i < 2048; i += 256) {
        uint32_t c = lh[i] + lh[2049 + i] + lh[2 * 2049 + i] + lh[3 * 2049 + i];
        if (c) atomicAdd(&hist[i], c);
    }
    __threadfence();
    if (threadIdx.x == 0) {
        s_last = (atomicAdd(ticket, 1u) == (uint32_t)gridDim.x - 1u) ? 1u : 0u;
        int kk = *kptr;
        sk = (kk > 0) ? (uint32_t)kk : 0u;
    }
    __syncthreads();
    if (!s_last) return;
    __threadfence();
    uint32_t* part = lh;
    uint32_t* sel = &lh[256];
    select_kth<2048>(hist, sk, part, sel);
    if (threadIdx.x == 0) {
        uint32_t k = sk, total = sel[2];
        if (k == 0u) {
            st->u_kth = 0xFFFFFFFFu; st->thr_nl = __int_as_float(0x7F800000); st->done = 1u;
        } else if (k > total) {
            st->u_kth = 0u; st->thr_nl = 0.0f; st->done = 1u;
        } else {
            st->prefix = sel[0]; st->k_rem = sel[1];  // done stays 0
        }
    }
}

__global__ __launch_bounds__(256) void k2_refine(
        const float* __restrict__ x, const float* __restrict__ t,
        const uint32_t* __restrict__ uvals, uint32_t* __restrict__ hist,
        uint32_t* __restrict__ ticket, SelState* __restrict__ st, int n) {
    __shared__ uint32_t lh[8192];
    __shared__ uint32_t s_last, s_prefix, s_krem, s_done;
    if (threadIdx.x == 0) { s_prefix = st->prefix; s_krem = st->k_rem; s_done = st->done; }
    __syncthreads();
    if (s_done) return;
    const uint32_t prefix = s_prefix;
    for (int i = threadIdx.x; i < 8192; i += 256) lh[i] = 0;
    __syncthreads();

    const int n4 = n >> 2;
    const int stride = gridDim.x * 256;
    if (uvals) {
        for (int i = blockIdx.x * 256 + threadIdx.x; i < n4; i += stride) {
            uint4 u = ((const uint4*)uvals)[i];
            if (u.x && (u.x >> 21) == prefix) atomicAdd(&lh[(u.x >> 8) & 8191u], 1u);
            if (u.y && (u.y >> 21) == prefix) atomicAdd(&lh[(u.y >> 8) & 8191u], 1u);
            if (u.z && (u.z >> 21) == prefix) atomicAdd(&lh[(u.z >> 8) & 8191u], 1u);
            if (u.w && (u.w >> 21) == prefix) atomicAdd(&lh[(u.w >> 8) & 8191u], 1u);
        }
        if (blockIdx.x == 0) {
            for (int i = (n4 << 2) + threadIdx.x; i < n; i += 256) {
                uint32_t u = uvals[i];
                if (u && (u >> 21) == prefix) atomicAdd(&lh[(u >> 8) & 8191u], 1u);
            }
        }
    } else {
        for (int i = blockIdx.x * 256 + threadIdx.x; i < n4; i += stride) {
            float4 xv = ((const float4*)x)[i];
            float4 tv = ((const float4*)t)[i];
            uint32_t u0 = (tv.x < 0.0f) ? xform(__float_as_uint(xv.x)) : 0u;
            uint32_t u1 = (tv.y < 0.0f) ? xform(__float_as_uint(xv.y)) : 0u;
            uint32_t u2 = (tv.z < 0.0f) ? xform(__float_as_uint(xv.z)) : 0u;
            uint32_t u3 = (tv.w < 0.0f) ? xform(__float_as_uint(xv.w)) : 0u;
            if (u0 && (u0 >> 21) == prefix) atomicAdd(&lh[(u0 >> 8) & 8191u], 1u);
            if (u1 && (u1 >> 21) == prefix) atomicAdd(&lh[(u1 >> 8) & 8191u], 1u);
            if (u2 && (u2 >> 21) == prefix) atomicAdd(&lh[(u2 >> 8) & 8191u], 1u);
            if (u3 && (u3 >> 21) == prefix) atomicAdd(&lh[(u3 >> 8) & 8191u], 1u);
        }
        if (blockIdx.x == 0) {
            for (int i = (n4 << 2) + threadIdx.x; i < n; i += 256) {
                uint32_t u = (t[i] < 0.0f) ? xform(__float_as_uint(x[i])) : 0u;
                if (u && (u >> 21) == prefix) atomicAdd(&lh[(u >> 8) & 8191u], 1u);
            }
        }
    }
    __syncthreads();
    for (int i = threadIdx.x; i < 8192; i += 256) {
        uint32_t c = lh[i];
        if (c) atomicAdd(&hist[i], c);
    }
    __threadfence();
    if (threadIdx.x == 0) s_last = (atomicAdd(ticket, 1u) == (uint32_t)gridDim.x - 1u) ? 1u : 0u;
    __syncthreads();
    if (!s_last) return;
    __threadfence();
    uint32_t* part = lh;
    uint32_t* sel = &lh[256];
    select_kth<8192>(hist, s_krem, part, sel);
    if (threadIdx.x == 0) {
        st->prefix = (prefix << 13) | sel[0];   // 24 bits now
        st->k_rem = sel[1];
    }
}

__global__ __launch_bounds__(256) void k3_refine(
        const float* __restrict__ x, const float* __restrict__ t,
        const uint32_t* __restrict__ uvals, uint32_t* __restrict__ hist,
        uint32_t* __restrict__ ticket, SelState* __restrict__ st, int n) {
    __shared__ uint32_t lh[768];  // [0,256) hist, [256,512) part, [512,515) sel
    __shared__ uint32_t s_last, s_prefix, s_krem, s_done;
    if (threadIdx.x == 0) { s_prefix = st->prefix; s_krem = st->k_rem; s_done = st->done; }
    __syncthreads();
    if (s_done) return;
    const uint32_t prefix = s_prefix;  // 24 bits
    if (threadIdx.x < 256) lh[threadIdx.x] = 0;
    __syncthreads();

    const int n4 = n >> 2;
    const int stride = gridDim.x * 256;
    if (uvals) {
        for (int i = blockIdx.x * 256 + threadIdx.x; i < n4; i += stride) {
            uint4 u = ((const uint4*)uvals)[i];
            if (u.x && (u.x >> 8) == prefix) atomicAdd(&lh[u.x & 255u], 1u);
            if (u.y && (u.y >> 8) == prefix) atomicAdd(&lh[u.y & 255u], 1u);
            if (u.z && (u.z >> 8) == prefix) atomicAdd(&lh[u.z & 255u], 1u);
            if (u.w && (u.w >> 8) == prefix) atomicAdd(&lh[u.w & 255u], 1u);
        }
        if (blockIdx.x == 0) {
            for (int i = (n4 << 2) + threadIdx.x; i < n; i += 256) {
                uint32_t u = uvals[i];
                if (u && (u >> 8) == prefix) atomicAdd(&lh[u & 255u], 1u);
            }
        }
    } else {
        for (int i = blockIdx.x * 256 + threadIdx.x; i < n4; i += stride) {
            float4 xv = ((const float4*)x)[i];
            float4 tv = ((const float4*)t)[i];
            uint32_t u0 = (tv.x < 0.0f) ? xform(__float_as_uint(xv.x)) : 0u;
            uint32_t u1 = (tv.y < 0.0f) ? xform(__float_as_uint(xv.y)) : 0u;
            uint32_t u2 = (tv.z < 0.0f) ? xform(__float_as_uint(xv.z)) : 0u;
            uint32_t u3 = (tv.w < 0.0f) ? xform(__float_as_uint(xv.w)) : 0u;
            if (u0 && (u0 >> 8) == prefix) atomicAdd(&lh[u0 & 255u], 1u);
            if (u1 && (u1 >> 8) == prefix) atomicAdd(&lh[u1 & 255u], 1u);
            if (u2 && (u2 >> 8) == prefix) atomicAdd(&lh[u2 & 255u], 1u);
            if (u3 && (u3 >> 8) == prefix) atomicAdd(&lh[u3 & 255u], 1u);
        }
        if (blockIdx.x == 0) {
            for (int i = (n4 << 2) + threadIdx.x; i < n; i += 256) {
                uint32_t u = (t[i] < 0.0f) ? xform(__float_as_uint(x[i])) : 0u;
                if (u && (u >> 8) == prefix) atomicAdd(&lh[u & 255u], 1u);
            }
        }
    }
    __syncthreads();
    {
        uint32_t c = lh[threadIdx.x & 255u];
        if (threadIdx.x < 256 && c) atomicAdd(&hist[threadIdx.x], c);
    }
    __threadfence();
    if (threadIdx.x == 0) s_last = (atomicAdd(ticket, 1u) == (uint32_t)gridDim.x - 1u) ? 1u : 0u;
    __syncthreads();
    if (!s_last) return;
    __threadfence();
    uint32_t* part = &lh[256];
    uint32_t* sel = &lh[512];
    select_kth<256>(hist, s_krem, part, sel);
    if (threadIdx.x == 0) {
        uint32_t u_kth = (prefix << 8) | sel[0];
        st->u_kth = u_kth;
        st->thr_nl = neg_loss_precise(unxform(u_kth), -1.0f);  // t=-1 exactly
        st->done = 1u;
    }
}

__global__ __launch_bounds__(256) void k4_final(
        const float* __restrict__ x, const float* __restrict__ t,
        const SelState* __restrict__ st, float* __restrict__ out, int n) {
    const uint32_t ukth = st->u_kth;
    const float thr = st->thr_nl;
    const int n4 = n >> 2;
    const int stride = gridDim.x * 256;
    for (int i = blockIdx.x * 256 + threadIdx.x; i < n4; i += stride) {
        float4 xv = ((const float4*)x)[i];
        float4 tv = ((const float4*)t)[i];
        float4 r;
        float* rp = &r.x;
        const float* xp = &xv.x;
        const float* tp = &tv.x;
#pragma unroll
        for (int j = 0; j < 4; ++j) {
            float xx = xp[j], tt = tp[j];
            float lp = __logf(1.0f + __expf(-fabsf(xx)));   // fast HW exp/log
            float v = 0.0f;
            if (tt > 0.0f) {
                v = fmaxf(xx, 0.0f) - xx * tt + lp;
            } else if (tt < 0.0f) {
                uint32_t u = xform(__float_as_uint(xx));
                bool keep = u < ukth;
                if (keep && (ukth - u) < GUARD)             // ~0 lanes: exact boundary
                    keep = neg_loss_precise(xx, tt) < thr;
                if (keep) v = fmaxf(-xx, 0.0f) - xx * tt + lp;
            }
            rp[j] = v;
        }
        ((float4*)out)[i] = r;
    }
    if (blockIdx.x == 0) {
        for (int i = (n4 << 2) + threadIdx.x; i < n; i += 256) {
            float xx = x[i], tt = t[i];
            float lp = __logf(1.0f + __expf(-fabsf(xx)));
            float v = 0.0f;
            if (tt > 0.0f) {
                v = fmaxf(xx, 0.0f) - xx * tt + lp;
            } else if (tt < 0.0f) {
                uint32_t u = xform(__float_as_uint(xx));
                bool keep = u < ukth;
                if (keep && (ukth - u) < GUARD)
                    keep = neg_loss_precise(xx, tt) < thr;
                if (keep) v = fmaxf(-xx, 0.0f) - xx * tt + lp;
            }
            out[i] = v;
        }
    }
}

extern "C" void kernel_launch(void* const* d_in, const int* in_sizes, int n_in,
                              void* d_out, int out_size, void* d_ws, size_t ws_size,
                              hipStream_t stream) {
    const float* x = (const float*)d_in[0];
    const float* t = (const float*)d_in[1];
    const int* kptr = (const int*)d_in[2];
    float* out = (float*)d_out;
    const int n = in_sizes[0];
    if (n <= 0) return;

    char* ws = (char*)d_ws;
    uint32_t* hist1 = (uint32_t*)(ws + 0);
    uint32_t* hist2 = (uint32_t*)(ws + 8192);
    uint32_t* hist3 = (uint32_t*)(ws + 40960);
    SelState* st    = (SelState*)(ws + 41984);
    uint32_t* tick  = (uint32_t*)(ws + 42112);
    const bool cached = ws_size >= (size_t)49152 + (size_t)n * 4u;
    uint32_t* uvals = cached ? (uint32_t*)(ws + 49152) : nullptr;

    hipMemsetAsync(d_ws, 0, 43008, stream);  // hists + state + tickets

    const int n4 = n >> 2;
    int work = (n4 + 255) / 256;
    if (work < 1) work = 1;
    int g1 = work < 1024 ? work : 1024;   // 32.8 KB LDS -> 4 blocks/CU
    int g2 = work < 1024 ? work : 1024;
    int g3 = work < 1024 ? work : 1024;
    int g4 = work < 2048 ? work : 2048;

    k1_hist  <<<g1, 256, 0, stream>>>(x, t, uvals, hist1, &tick[0], st, kptr, n);
    k2_refine<<<g2, 256, 0, stream>>>(x, t, uvals, hist2, &tick[1], st, n);
    k3_refine<<<g3, 256, 0, stream>>>(x, t, uvals, hist3, &tick[2], st, n);
    k4_final <<<g4, 256, 0, stream>>>(x, t, st, out, n);
}

// Round 4
// 206.417 us; speedup vs baseline: 1.8619x; 1.8619x over previous
//
#include <hip/hip_runtime.h>
#include <cstdint>

// Exact radix-select (11+11+10 bits) on order-transformed x bits among t<0
// entries (t = -1 exactly => negative_loss = softplus(x), strictly increasing
// in x). 7 dispatches + memset: hist/scan/refine/scan/refine/scan/final.
// No device-scope fences, no fused tails (R3 lesson). All heavy kernels are
// 8-KB-to-16-KB LDS so occupancy stays wave-limited (8 blocks/CU).
// Final pass: fast __expf/__logf for VALUES, exact bit-compare for the MASK,
// precise log1pf re-check only within a 256-ulp guard band at the boundary.
//
// ws layout:
//   [0     ..  8192)  hist1 (2048 u32)   bits [31:21]
//   [8192  .. 16384)  hist2 (2048 u32)   bits [20:10]
//   [16384 .. 20480)  hist3 (1024 u32)   bits [9:0]
//   [20480 .. 20544)  SelState
//   [24576 .. 24576+4N)  cached u-vals (0 sentinel for t>=0)

struct SelState {
    uint32_t prefix;   // selected high bits so far
    uint32_t k_rem;    // remaining rank within selected bin
    uint32_t u_kth;    // final: transformed bits of k-th largest x
    float    thr_nl;   // final: precise loss-space threshold
    uint32_t done;
};

#define GUARD 256u

__device__ __forceinline__ uint32_t xform(uint32_t b) {
    return ((int32_t)b < 0) ? ~b : (b | 0x80000000u);
}
__device__ __forceinline__ float unxform(uint32_t u) {
    uint32_t b = (u & 0x80000000u) ? (u ^ 0x80000000u) : ~u;
    return __uint_as_float(b);
}
// precise chain — matches reference fp32 semantics; used only for the
// threshold value and the rare guard-band compare.
__device__ __forceinline__ float neg_loss_precise(float x, float t) {
#pragma clang fp contract(off)
    return (fmaxf(-x, 0.0f) - x * t) + log1pf(expf(-fabsf(x)));
}

// ---------------- k1: 11-bit histogram + uvals cache ----------------
__global__ __launch_bounds__(256) void k1_hist(
        const float* __restrict__ x, const float* __restrict__ t,
        uint32_t* __restrict__ uvals, uint32_t* __restrict__ hist, int n) {
    __shared__ uint32_t lh[2 * 2049];   // 2-way replicated (+1 pad), 16.4 KB
    for (int i = threadIdx.x; i < 2 * 2049; i += 256) lh[i] = 0;
    __syncthreads();
    uint32_t* my = &lh[(threadIdx.x & 1) * 2049];

    const int n4 = n >> 2;
    const int stride = gridDim.x * 256;
    for (int i = blockIdx.x * 256 + threadIdx.x; i < n4; i += stride) {
        float4 xv = ((const float4*)x)[i];
        float4 tv = ((const float4*)t)[i];
        uint32_t u0 = (tv.x < 0.0f) ? xform(__float_as_uint(xv.x)) : 0u;
        uint32_t u1 = (tv.y < 0.0f) ? xform(__float_as_uint(xv.y)) : 0u;
        uint32_t u2 = (tv.z < 0.0f) ? xform(__float_as_uint(xv.z)) : 0u;
        uint32_t u3 = (tv.w < 0.0f) ? xform(__float_as_uint(xv.w)) : 0u;
        if (uvals) ((uint4*)uvals)[i] = make_uint4(u0, u1, u2, u3);
        if (u0) atomicAdd(&my[u0 >> 21], 1u);
        if (u1) atomicAdd(&my[u1 >> 21], 1u);
        if (u2) atomicAdd(&my[u2 >> 21], 1u);
        if (u3) atomicAdd(&my[u3 >> 21], 1u);
    }
    if (blockIdx.x == 0) {  // tail (n % 4)
        for (int i = (n4 << 2) + threadIdx.x; i < n; i += 256) {
            uint32_t u = (t[i] < 0.0f) ? xform(__float_as_uint(x[i])) : 0u;
            if (uvals) uvals[i] = u;
            if (u) atomicAdd(&my[u >> 21], 1u);
        }
    }
    __syncthreads();
    for (int i = threadIdx.x; i < 2048; i += 256) {
        uint32_t c = lh[i] + lh[2049 + i];
        if (c) atomicAdd(&hist[i], c);
    }
}

// ---------------- refine: histogram lower bits of matching prefix ----------------
__global__ __launch_bounds__(256) void k_refine(
        const float* __restrict__ x, const float* __restrict__ t,
        const uint32_t* __restrict__ uvals, uint32_t* __restrict__ hist,
        const SelState* __restrict__ st, int n,
        int match_shift, int bin_shift, uint32_t bin_mask) {
    __shared__ uint32_t lh[2048];
    __shared__ uint32_t s_prefix, s_done;
    if (threadIdx.x == 0) { s_prefix = st->prefix; s_done = st->done; }
    __syncthreads();
    if (s_done) return;  // uniform
    const uint32_t prefix = s_prefix;
    for (int i = threadIdx.x; i <= (int)bin_mask; i += 256) lh[i] = 0;
    __syncthreads();

    const int n4 = n >> 2;
    const int stride = gridDim.x * 256;
    if (uvals) {
        for (int i = blockIdx.x * 256 + threadIdx.x; i < n4; i += stride) {
            uint4 u = ((const uint4*)uvals)[i];
            if (u.x && (u.x >> match_shift) == prefix) atomicAdd(&lh[(u.x >> bin_shift) & bin_mask], 1u);
            if (u.y && (u.y >> match_shift) == prefix) atomicAdd(&lh[(u.y >> bin_shift) & bin_mask], 1u);
            if (u.z && (u.z >> match_shift) == prefix) atomicAdd(&lh[(u.z >> bin_shift) & bin_mask], 1u);
            if (u.w && (u.w >> match_shift) == prefix) atomicAdd(&lh[(u.w >> bin_shift) & bin_mask], 1u);
        }
        if (blockIdx.x == 0) {
            for (int i = (n4 << 2) + threadIdx.x; i < n; i += 256) {
                uint32_t u = uvals[i];
                if (u && (u >> match_shift) == prefix) atomicAdd(&lh[(u >> bin_shift) & bin_mask], 1u);
            }
        }
    } else {
        for (int i = blockIdx.x * 256 + threadIdx.x; i < n4; i += stride) {
            float4 xv = ((const float4*)x)[i];
            float4 tv = ((const float4*)t)[i];
            uint32_t u0 = (tv.x < 0.0f) ? xform(__float_as_uint(xv.x)) : 0u;
            uint32_t u1 = (tv.y < 0.0f) ? xform(__float_as_uint(xv.y)) : 0u;
            uint32_t u2 = (tv.z < 0.0f) ? xform(__float_as_uint(xv.z)) : 0u;
            uint32_t u3 = (tv.w < 0.0f) ? xform(__float_as_uint(xv.w)) : 0u;
            if (u0 && (u0 >> match_shift) == prefix) atomicAdd(&lh[(u0 >> bin_shift) & bin_mask], 1u);
            if (u1 && (u1 >> match_shift) == prefix) atomicAdd(&lh[(u1 >> bin_shift) & bin_mask], 1u);
            if (u2 && (u2 >> match_shift) == prefix) atomicAdd(&lh[(u2 >> bin_shift) & bin_mask], 1u);
            if (u3 && (u3 >> match_shift) == prefix) atomicAdd(&lh[(u3 >> bin_shift) & bin_mask], 1u);
        }
        if (blockIdx.x == 0) {
            for (int i = (n4 << 2) + threadIdx.x; i < n; i += 256) {
                uint32_t u = (t[i] < 0.0f) ? xform(__float_as_uint(x[i])) : 0u;
                if (u && (u >> match_shift) == prefix) atomicAdd(&lh[(u >> bin_shift) & bin_mask], 1u);
            }
        }
    }
    __syncthreads();
    for (int i = threadIdx.x; i <= (int)bin_mask; i += 256) {
        uint32_t c = lh[i];
        if (c) atomicAdd(&hist[i], c);
    }
}

// ---------------- scan: 1 block, find bin holding the k-th LARGEST ----------------
// level 0: k from kptr (k==0 -> +inf keep-all; k>total -> 0 drop-all), stores 11-bit prefix
// level 1: prefix = (prefix<<11)|bin ; level 2: u_kth = (prefix<<10)|bin, thr_nl, done.
template<int CH>
__global__ __launch_bounds__(256) void k_scan(
        const uint32_t* __restrict__ hist, SelState* __restrict__ st,
        const int* __restrict__ kptr, int level) {
    __shared__ uint32_t part[256];
    __shared__ SelState sst;
    __shared__ uint32_t sk;
    const int tid = threadIdx.x;
    if (tid == 0) {
        sst = *st;
        if (level == 0) {
            int kk = *kptr;
            sk = (kk > 0) ? (uint32_t)kk : 0u;
        } else {
            sk = sst.k_rem;
        }
    }
    __syncthreads();
    if (level > 0 && sst.done) return;
    const uint32_t k = sk;

    uint32_t cnt[CH];
    uint32_t lsum = 0;
#pragma unroll
    for (int j = 0; j < CH; ++j) {
        cnt[j] = hist[tid * CH + j];
        lsum += cnt[j];
    }
    part[tid] = lsum;
    __syncthreads();
    for (int off = 1; off < 256; off <<= 1) {  // inclusive suffix sum
        uint32_t add = (tid + off < 256) ? part[tid + off] : 0u;
        __syncthreads();
        part[tid] += add;
        __syncthreads();
    }
    const uint32_t total = part[0];

    if (level == 0) {
        if (k == 0u) {
            if (tid == 0) { st->u_kth = 0xFFFFFFFFu; st->thr_nl = __int_as_float(0x7F800000); st->done = 1u; }
            return;
        }
        if (k > total) {
            if (tid == 0) { st->u_kth = 0u; st->thr_nl = 0.0f; st->done = 1u; }
            return;
        }
    }

    uint32_t A = (tid < 255) ? part[tid + 1] : 0u;  // strictly-above count
#pragma unroll
    for (int j = CH - 1; j >= 0; --j) {
        uint32_t c = cnt[j];
        if (A < k && k <= A + c) {  // exactly one (thread,bin) hits
            uint32_t bin = (uint32_t)(tid * CH + j);
            uint32_t krem = k - A;
            if (level == 0) {
                st->prefix = bin;                       // 11 bits
                st->k_rem = krem;
            } else if (level == 1) {
                st->prefix = (sst.prefix << 11) | bin;  // 22 bits
                st->k_rem = krem;
            } else {
                uint32_t u_kth = (sst.prefix << 10) | bin;  // 32 bits
                st->u_kth = u_kth;
                st->thr_nl = neg_loss_precise(unxform(u_kth), -1.0f);
                st->done = 1u;
            }
        }
        A += c;
    }
}

// ---------------- final: fast-math values, bit-exact mask ----------------
__global__ __launch_bounds__(256) void k4_final(
        const float* __restrict__ x, const float* __restrict__ t,
        const SelState* __restrict__ st, float* __restrict__ out, int n) {
    const uint32_t ukth = st->u_kth;
    const float thr = st->thr_nl;
    const int n4 = n >> 2;
    const int stride = gridDim.x * 256;
    for (int i = blockIdx.x * 256 + threadIdx.x; i < n4; i += stride) {
        float4 xv = ((const float4*)x)[i];
        float4 tv = ((const float4*)t)[i];
        float4 r;
        float* rp = &r.x;
        const float* xp = &xv.x;
        const float* tp = &tv.x;
#pragma unroll
        for (int j = 0; j < 4; ++j) {
            float xx = xp[j], tt = tp[j];
            float lp = __logf(1.0f + __expf(-fabsf(xx)));   // HW exp/log
            float v = 0.0f;
            if (tt > 0.0f) {
                v = fmaxf(xx, 0.0f) - xx * tt + lp;
            } else if (tt < 0.0f) {
                uint32_t u = xform(__float_as_uint(xx));
                bool keep = u < ukth;
                if (keep && (ukth - u) < GUARD)             // ~0 lanes hit this
                    keep = neg_loss_precise(xx, tt) < thr;
                if (keep) v = fmaxf(-xx, 0.0f) - xx * tt + lp;
            }
            rp[j] = v;
        }
        ((float4*)out)[i] = r;
    }
    if (blockIdx.x == 0) {
        for (int i = (n4 << 2) + threadIdx.x; i < n; i += 256) {
            float xx = x[i], tt = t[i];
            float lp = __logf(1.0f + __expf(-fabsf(xx)));
            float v = 0.0f;
            if (tt > 0.0f) {
                v = fmaxf(xx, 0.0f) - xx * tt + lp;
            } else if (tt < 0.0f) {
                uint32_t u = xform(__float_as_uint(xx));
                bool keep = u < ukth;
                if (keep && (ukth - u) < GUARD)
                    keep = neg_loss_precise(xx, tt) < thr;
                if (keep) v = fmaxf(-xx, 0.0f) - xx * tt + lp;
            }
            out[i] = v;
        }
    }
}

extern "C" void kernel_launch(void* const* d_in, const int* in_sizes, int n_in,
                              void* d_out, int out_size, void* d_ws, size_t ws_size,
                              hipStream_t stream) {
    const float* x = (const float*)d_in[0];
    const float* t = (const float*)d_in[1];
    const int* kptr = (const int*)d_in[2];
    float* out = (float*)d_out;
    const int n = in_sizes[0];
    if (n <= 0) return;

    char* ws = (char*)d_ws;
    uint32_t* hist1 = (uint32_t*)(ws + 0);       // 2048 bins
    uint32_t* hist2 = (uint32_t*)(ws + 8192);    // 2048 bins
    uint32_t* hist3 = (uint32_t*)(ws + 16384);   // 1024 bins
    SelState* st    = (SelState*)(ws + 20480);
    const bool cached = ws_size >= (size_t)24576 + (size_t)n * 4u;
    uint32_t* uvals = cached ? (uint32_t*)(ws + 24576) : nullptr;

    hipMemsetAsync(d_ws, 0, 20544, stream);  // hists + state

    const int n4 = n >> 2;
    int work = (n4 + 255) / 256;
    if (work < 1) work = 1;
    int grid = work < 2048 ? work : 2048;    // 8 blocks/CU resident, grid-stride

    k1_hist <<<grid, 256, 0, stream>>>(x, t, uvals, hist1, n);
    k_scan<8><<<1, 256, 0, stream>>>(hist1, st, kptr, 0);
    k_refine<<<grid, 256, 0, stream>>>(x, t, uvals, hist2, st, n, 21, 10, 0x7FFu);
    k_scan<8><<<1, 256, 0, stream>>>(hist2, st, kptr, 1);
    k_refine<<<grid, 256, 0, stream>>>(x, t, uvals, hist3, st, n, 10, 0, 0x3FFu);
    k_scan<4><<<1, 256, 0, stream>>>(hist3, st, kptr, 2);
    k4_final<<<grid, 256, 0, stream>>>(x, t, st, out, n);
}

// Round 5
// 177.286 us; speedup vs baseline: 2.1678x; 1.1643x over previous
//
#include <hip/hip_runtime.h>
#include <cstdint>

// Exact radix-select on order-transformed x bits among t<0 entries
// (t = -1 exactly => negative_loss = softplus(x), strictly increasing in x).
// Level 1: 2048-bin (11-bit) LDS histogram over x,t (82 MB read).
// Level 2: single pass scatters prefix-matching elements (~k/10 of N) into a
//          2^21-bin GLOBAL histogram (8 MB) -> fully determines u_kth.
// All streaming loops are 4x unrolled with independent loads (MLP fix for the
// latency-bound 1.5 TB/s observed in R4). No uvals cache (saves 41 MB write).
// Final pass: fast __expf/__logf values, exact bit-compare mask, precise
// log1pf re-check only within a 256-ulp guard band at the boundary.
//
// ws layout:
//   [0     ..  8192)   hist1  (2048 u32)  bits [31:21]
//   [8192  .. 12288)   csums  (1024 u32)  per-chunk sums of hist21
//   [12288 .. 12352)   SelState
//   [16384 .. 16384+8MB) hist21 (2^21 u32) bits [20:0]

struct SelState {
    uint32_t prefix;   // 11-bit level-1 prefix
    uint32_t k_rem;    // remaining rank within selected bin
    uint32_t u_kth;    // final: transformed bits of k-th largest x
    float    thr_nl;   // final: precise loss-space threshold
    uint32_t done;
};

#define GUARD 256u

__device__ __forceinline__ uint32_t xform(uint32_t b) {
    return ((int32_t)b < 0) ? ~b : (b | 0x80000000u);
}
__device__ __forceinline__ float unxform(uint32_t u) {
    uint32_t b = (u & 0x80000000u) ? (u ^ 0x80000000u) : ~u;
    return __uint_as_float(b);
}
// precise chain — matches reference fp32 semantics; used only for the
// threshold value and the rare guard-band compare.
__device__ __forceinline__ float neg_loss_precise(float x, float t) {
#pragma clang fp contract(off)
    return (fmaxf(-x, 0.0f) - x * t) + log1pf(expf(-fabsf(x)));
}

// ---------------- k1: 11-bit LDS histogram (no uvals write) ----------------
__device__ __forceinline__ void hist_quad(uint32_t* my, float4 xv, float4 tv) {
    uint32_t u0 = (tv.x < 0.0f) ? xform(__float_as_uint(xv.x)) : 0u;
    uint32_t u1 = (tv.y < 0.0f) ? xform(__float_as_uint(xv.y)) : 0u;
    uint32_t u2 = (tv.z < 0.0f) ? xform(__float_as_uint(xv.z)) : 0u;
    uint32_t u3 = (tv.w < 0.0f) ? xform(__float_as_uint(xv.w)) : 0u;
    if (u0) atomicAdd(&my[u0 >> 21], 1u);
    if (u1) atomicAdd(&my[u1 >> 21], 1u);
    if (u2) atomicAdd(&my[u2 >> 21], 1u);
    if (u3) atomicAdd(&my[u3 >> 21], 1u);
}

__global__ __launch_bounds__(256) void k1_hist(
        const float* __restrict__ x, const float* __restrict__ t,
        uint32_t* __restrict__ hist, int n) {
    __shared__ uint32_t lh[2 * 2049];   // 2-way replicated (+1 pad)
    for (int i = threadIdx.x; i < 2 * 2049; i += 256) lh[i] = 0;
    __syncthreads();
    uint32_t* my = &lh[(threadIdx.x & 1) * 2049];

    const float4* x4 = (const float4*)x;
    const float4* t4 = (const float4*)t;
    const int n4 = n >> 2;
    const int S = gridDim.x * 256;
    int i = blockIdx.x * 256 + threadIdx.x;
    for (; i + 3 * S < n4; i += 4 * S) {       // 8 independent 16B loads in flight
        float4 xa = x4[i], xb = x4[i + S], xc = x4[i + 2 * S], xd = x4[i + 3 * S];
        float4 ta = t4[i], tb = t4[i + S], tc = t4[i + 2 * S], td = t4[i + 3 * S];
        hist_quad(my, xa, ta);
        hist_quad(my, xb, tb);
        hist_quad(my, xc, tc);
        hist_quad(my, xd, td);
    }
    for (; i < n4; i += S) {
        float4 xa = x4[i], ta = t4[i];
        hist_quad(my, xa, ta);
    }
    if (blockIdx.x == 0) {  // n % 4 tail
        for (int j = (n4 << 2) + threadIdx.x; j < n; j += 256) {
            uint32_t u = (t[j] < 0.0f) ? xform(__float_as_uint(x[j])) : 0u;
            if (u) atomicAdd(&my[u >> 21], 1u);
        }
    }
    __syncthreads();
    for (int b = threadIdx.x; b < 2048; b += 256) {
        uint32_t c = lh[b] + lh[2049 + b];
        if (c) atomicAdd(&hist[b], c);
    }
}

// ---------------- scan1: 1 block, pick 11-bit prefix ----------------
__global__ __launch_bounds__(256) void scan1(
        const uint32_t* __restrict__ hist, SelState* __restrict__ st,
        const int* __restrict__ kptr) {
    __shared__ uint32_t part[256];
    const int tid = threadIdx.x;
    uint32_t cnt[8];
    uint32_t lsum = 0;
#pragma unroll
    for (int j = 0; j < 8; ++j) { cnt[j] = hist[tid * 8 + j]; lsum += cnt[j]; }
    part[tid] = lsum;
    __syncthreads();
    for (int off = 1; off < 256; off <<= 1) {   // inclusive suffix sum
        uint32_t add = (tid + off < 256) ? part[tid + off] : 0u;
        __syncthreads();
        part[tid] += add;
        __syncthreads();
    }
    const uint32_t total = part[0];
    int kk = *kptr;
    uint32_t k = (kk > 0) ? (uint32_t)kk : 0u;
    if (k == 0u) {   // keep all negatives
        if (tid == 0) { st->u_kth = 0xFFFFFFFFu; st->thr_nl = __int_as_float(0x7F800000); st->done = 1u; }
        return;
    }
    if (k > total) { // drop all negatives
        if (tid == 0) { st->u_kth = 0u; st->thr_nl = 0.0f; st->done = 1u; }
        return;
    }
    uint32_t A = (tid < 255) ? part[tid + 1] : 0u;  // strictly-above count
#pragma unroll
    for (int j = 7; j >= 0; --j) {
        uint32_t c = cnt[j];
        if (A < k && k <= A + c) {   // exactly one (thread,bin)
            st->prefix = (uint32_t)(tid * 8 + j);
            st->k_rem = k - A;       // done stays 0 (memset)
        }
        A += c;
    }
}

// ---------------- k2: 21-bit global histogram of prefix-matching elems ----------------
__device__ __forceinline__ void cnt_quad(uint32_t* __restrict__ h21, uint32_t pref,
                                         float4 xv, float4 tv) {
    uint32_t u0 = (tv.x < 0.0f) ? xform(__float_as_uint(xv.x)) : 0u;
    uint32_t u1 = (tv.y < 0.0f) ? xform(__float_as_uint(xv.y)) : 0u;
    uint32_t u2 = (tv.z < 0.0f) ? xform(__float_as_uint(xv.z)) : 0u;
    uint32_t u3 = (tv.w < 0.0f) ? xform(__float_as_uint(xv.w)) : 0u;
    if (u0 && (u0 >> 21) == pref) atomicAdd(&h21[u0 & 0x1FFFFFu], 1u);
    if (u1 && (u1 >> 21) == pref) atomicAdd(&h21[u1 & 0x1FFFFFu], 1u);
    if (u2 && (u2 >> 21) == pref) atomicAdd(&h21[u2 & 0x1FFFFFu], 1u);
    if (u3 && (u3 >> 21) == pref) atomicAdd(&h21[u3 & 0x1FFFFFu], 1u);
}

__global__ __launch_bounds__(256) void k2_hist21(
        const float* __restrict__ x, const float* __restrict__ t,
        uint32_t* __restrict__ h21, const SelState* __restrict__ st, int n) {
    __shared__ uint32_t s_pref, s_done;
    if (threadIdx.x == 0) { s_pref = st->prefix; s_done = st->done; }
    __syncthreads();
    if (s_done) return;
    const uint32_t pref = s_pref;

    const float4* x4 = (const float4*)x;
    const float4* t4 = (const float4*)t;
    const int n4 = n >> 2;
    const int S = gridDim.x * 256;
    int i = blockIdx.x * 256 + threadIdx.x;
    for (; i + 3 * S < n4; i += 4 * S) {
        float4 xa = x4[i], xb = x4[i + S], xc = x4[i + 2 * S], xd = x4[i + 3 * S];
        float4 ta = t4[i], tb = t4[i + S], tc = t4[i + 2 * S], td = t4[i + 3 * S];
        cnt_quad(h21, pref, xa, ta);
        cnt_quad(h21, pref, xb, tb);
        cnt_quad(h21, pref, xc, tc);
        cnt_quad(h21, pref, xd, td);
    }
    for (; i < n4; i += S) {
        float4 xa = x4[i], ta = t4[i];
        cnt_quad(h21, pref, xa, ta);
    }
    if (blockIdx.x == 0) {
        for (int j = (n4 << 2) + threadIdx.x; j < n; j += 256) {
            uint32_t u = (t[j] < 0.0f) ? xform(__float_as_uint(x[j])) : 0u;
            if (u && (u >> 21) == pref) atomicAdd(&h21[u & 0x1FFFFFu], 1u);
        }
    }
}

// ---------------- scan2a: per-chunk sums of hist21 (1024 chunks x 2048 bins) ----------------
__global__ __launch_bounds__(256) void scan2a(
        const uint32_t* __restrict__ h21, uint32_t* __restrict__ csums,
        const SelState* __restrict__ st) {
    __shared__ uint32_t red[256];
    __shared__ uint32_t s_done;
    if (threadIdx.x == 0) s_done = st->done;
    __syncthreads();
    if (s_done) return;   // csums stays 0 (memset) — unused on this path
    const uint4* b4 = (const uint4*)(h21 + (size_t)blockIdx.x * 2048);
    uint32_t s = 0;
    for (int j = threadIdx.x; j < 512; j += 256) {
        uint4 v = b4[j];
        s += v.x + v.y + v.z + v.w;
    }
    red[threadIdx.x] = s;
    __syncthreads();
    for (int off = 128; off > 0; off >>= 1) {
        if (threadIdx.x < off) red[threadIdx.x] += red[threadIdx.x + off];
        __syncthreads();
    }
    if (threadIdx.x == 0) csums[blockIdx.x] = red[0];
}

// ---------------- scan2b: 1 block, pick chunk then bin -> u_kth ----------------
__global__ __launch_bounds__(256) void scan2b(
        const uint32_t* __restrict__ h21, const uint32_t* __restrict__ csums,
        SelState* __restrict__ st) {
    __shared__ uint32_t part[256];
    __shared__ uint32_t sel[2];
    __shared__ SelState sst;
    const int tid = threadIdx.x;
    if (tid == 0) sst = *st;
    __syncthreads();
    if (sst.done) return;
    const uint32_t k = sst.k_rem;

    // stage 1: 1024 chunk sums, 4 per thread
    uint32_t c4[4];
    uint32_t lsum = 0;
#pragma unroll
    for (int j = 0; j < 4; ++j) { c4[j] = csums[tid * 4 + j]; lsum += c4[j]; }
    part[tid] = lsum;
    __syncthreads();
    for (int off = 1; off < 256; off <<= 1) {
        uint32_t add = (tid + off < 256) ? part[tid + off] : 0u;
        __syncthreads();
        part[tid] += add;
        __syncthreads();
    }
    uint32_t A = (tid < 255) ? part[tid + 1] : 0u;
#pragma unroll
    for (int j = 3; j >= 0; --j) {
        uint32_t c = c4[j];
        if (A < k && k <= A + c) { sel[0] = (uint32_t)(tid * 4 + j); sel[1] = k - A; }
        A += c;
    }
    __syncthreads();
    const uint32_t chunk = sel[0];
    const uint32_t k2 = sel[1];
    __syncthreads();

    // stage 2: 2048 bins of the chosen chunk, 8 per thread
    const uint32_t* base = h21 + (size_t)chunk * 2048;
    uint32_t b8[8];
    lsum = 0;
#pragma unroll
    for (int j = 0; j < 8; ++j) { b8[j] = base[tid * 8 + j]; lsum += b8[j]; }
    part[tid] = lsum;
    __syncthreads();
    for (int off = 1; off < 256; off <<= 1) {
        uint32_t add = (tid + off < 256) ? part[tid + off] : 0u;
        __syncthreads();
        part[tid] += add;
        __syncthreads();
    }
    A = (tid < 255) ? part[tid + 1] : 0u;
#pragma unroll
    for (int j = 7; j >= 0; --j) {
        uint32_t c = b8[j];
        if (A < k2 && k2 <= A + c) {
            uint32_t u = (sst.prefix << 21) | (chunk * 2048u + (uint32_t)(tid * 8 + j));
            st->u_kth = u;
            st->thr_nl = neg_loss_precise(unxform(u), -1.0f);  // t = -1 exactly
            st->done = 1u;
        }
        A += c;
    }
}

// ---------------- final: fast-math values, bit-exact mask ----------------
__device__ __forceinline__ float fin1(float xx, float tt, uint32_t ukth, float thr) {
    float lp = __logf(1.0f + __expf(-fabsf(xx)));   // HW exp/log
    float v = 0.0f;
    if (tt > 0.0f) {
        v = fmaxf(xx, 0.0f) - xx * tt + lp;
    } else if (tt < 0.0f) {
        uint32_t u = xform(__float_as_uint(xx));
        bool keep = u < ukth;
        if (keep && (ukth - u) < GUARD)             // ~0 lanes hit this
            keep = neg_loss_precise(xx, tt) < thr;
        if (keep) v = fmaxf(-xx, 0.0f) - xx * tt + lp;
    }
    return v;
}

__device__ __forceinline__ float4 fin_quad(float4 xv, float4 tv, uint32_t ukth, float thr) {
    float4 r;
    r.x = fin1(xv.x, tv.x, ukth, thr);
    r.y = fin1(xv.y, tv.y, ukth, thr);
    r.z = fin1(xv.z, tv.z, ukth, thr);
    r.w = fin1(xv.w, tv.w, ukth, thr);
    return r;
}

__global__ __launch_bounds__(256) void k_final(
        const float* __restrict__ x, const float* __restrict__ t,
        const SelState* __restrict__ st, float* __restrict__ out, int n) {
    const uint32_t ukth = st->u_kth;
    const float thr = st->thr_nl;
    const float4* x4 = (const float4*)x;
    const float4* t4 = (const float4*)t;
    float4* o4 = (float4*)out;
    const int n4 = n >> 2;
    const int S = gridDim.x * 256;
    int i = blockIdx.x * 256 + threadIdx.x;
    for (; i + 3 * S < n4; i += 4 * S) {
        float4 xa = x4[i], xb = x4[i + S], xc = x4[i + 2 * S], xd = x4[i + 3 * S];
        float4 ta = t4[i], tb = t4[i + S], tc = t4[i + 2 * S], td = t4[i + 3 * S];
        o4[i]         = fin_quad(xa, ta, ukth, thr);
        o4[i + S]     = fin_quad(xb, tb, ukth, thr);
        o4[i + 2 * S] = fin_quad(xc, tc, ukth, thr);
        o4[i + 3 * S] = fin_quad(xd, td, ukth, thr);
    }
    for (; i < n4; i += S) {
        float4 xa = x4[i], ta = t4[i];
        o4[i] = fin_quad(xa, ta, ukth, thr);
    }
    if (blockIdx.x == 0) {
        for (int j = (n4 << 2) + threadIdx.x; j < n; j += 256) {
            out[j] = fin1(x[j], t[j], ukth, thr);
        }
    }
}

extern "C" void kernel_launch(void* const* d_in, const int* in_sizes, int n_in,
                              void* d_out, int out_size, void* d_ws, size_t ws_size,
                              hipStream_t stream) {
    const float* x = (const float*)d_in[0];
    const float* t = (const float*)d_in[1];
    const int* kptr = (const int*)d_in[2];
    float* out = (float*)d_out;
    const int n = in_sizes[0];
    if (n <= 0) return;

    char* ws = (char*)d_ws;
    uint32_t* hist1 = (uint32_t*)(ws + 0);        // 2048 bins
    uint32_t* csums = (uint32_t*)(ws + 8192);     // 1024 chunk sums
    SelState* st    = (SelState*)(ws + 12288);
    uint32_t* h21   = (uint32_t*)(ws + 16384);    // 2^21 bins (8 MB)

    // zero hist1 + csums + state + hist21 (one memset, ~8.4 MB)
    hipMemsetAsync(d_ws, 0, 16384 + (size_t)(1u << 21) * 4u, stream);

    const int n4 = n >> 2;
    int work = (n4 + 255) / 256;
    if (work < 1) work = 1;
    int grid = work < 1024 ? work : 1024;   // 4 blocks/CU; x4 unroll covers depth

    k1_hist  <<<grid, 256, 0, stream>>>(x, t, hist1, n);
    scan1    <<<1, 256, 0, stream>>>(hist1, st, kptr);
    k2_hist21<<<grid, 256, 0, stream>>>(x, t, h21, st, n);
    scan2a   <<<1024, 256, 0, stream>>>(h21, csums, st);
    scan2b   <<<1, 256, 0, stream>>>(h21, csums, st);
    k_final  <<<grid, 256, 0, stream>>>(x, t, st, out, n);
}